// Round 2
// baseline (18.993 us; speedup 1.0000x reference)
//
#include <hip/hip_runtime.h>

// Problem constants (from reference)
#define VCAP 1000000
#define DIM  128
#define BATCH 4096
#define BAG  20
#define NFEAT 2
#define HALF_BAG (BAG / 2)

// One 64-lane wave per (feature, batch-row) output row.
// Lanes 0-31 accumulate bag elements 0..9, lanes 32-63 accumulate 10..19;
// each lane owns one float4 chunk (sub = lane&31 -> 32 x float4 = 128 floats).
// Halves combined with 4 shfl_xor(32); lanes 0-31 store the row.
// Grid: 8192 rows / 4 waves-per-block = 2048 blocks of 256 threads
// -> 8 blocks/CU -> 32 waves/CU (100% occupancy) for max MLP on the
// random gathers.
__global__ __launch_bounds__(256) void emb_pool_kernel(
    const int* __restrict__ indices,   // [F, B, L] int32
    const float* __restrict__ table0,  // [V, D]
    const float* __restrict__ table1,  // [V, D]
    float* __restrict__ out)           // [B, F*D]
{
    const int row  = blockIdx.x * 4 + (threadIdx.x >> 6);  // (f,b) pair id
    const int lane = threadIdx.x & 63;
    const int half = lane >> 5;   // which bag half this lane sums
    const int sub  = lane & 31;   // float4 chunk within the 128-float row

    const int f = row >> 12;          // row / 4096
    const int b = row & (BATCH - 1);  // row % 4096

    const float* __restrict__ tab = (f == 0) ? table0 : table1;
    const int* __restrict__ idxp =
        indices + (size_t)row * BAG + half * HALF_BAG;

    float4 acc = make_float4(0.f, 0.f, 0.f, 0.f);
    #pragma unroll
    for (int l = 0; l < HALF_BAG; ++l) {
        const int idx = idxp[l];
        const float4 v =
            reinterpret_cast<const float4*>(tab + (size_t)idx * DIM)[sub];
        acc.x += v.x; acc.y += v.y; acc.z += v.z; acc.w += v.w;
    }

    // Combine the two bag halves across the wave (lane i <-> lane i^32).
    acc.x += __shfl_xor(acc.x, 32, 64);
    acc.y += __shfl_xor(acc.y, 32, 64);
    acc.z += __shfl_xor(acc.z, 32, 64);
    acc.w += __shfl_xor(acc.w, 32, 64);

    if (half == 0) {
        reinterpret_cast<float4*>(
            out + (size_t)b * (NFEAT * DIM) + f * DIM)[sub] = acc;
    }
}

extern "C" void kernel_launch(void* const* d_in, const int* in_sizes, int n_in,
                              void* d_out, int out_size, void* d_ws, size_t ws_size,
                              hipStream_t stream) {
    const int*   indices = (const int*)d_in[0];
    const float* table0  = (const float*)d_in[1];
    const float* table1  = (const float*)d_in[2];
    float*       out     = (float*)d_out;

    const int rows   = NFEAT * BATCH;  // 8192 waves
    const int blocks = rows / 4;       // 2048 blocks of 256 threads (4 waves)
    emb_pool_kernel<<<blocks, 256, 0, stream>>>(indices, table0, table1, out);
}

// Round 3
// 18.805 us; speedup vs baseline: 1.0100x; 1.0100x over previous
//
#include <hip/hip_runtime.h>

// Problem constants (from reference)
#define VCAP 1000000
#define DIM  128
#define BATCH 4096
#define BAG  20
#define NFEAT 2

// One 64-lane wave per (feature, batch-row) output row.
// ALL 64 lanes read the SAME table row per bag element: lane covers one
// float2 (8 B), 64 lanes x 8 B = exactly one 512 B contiguous segment per
// VMEM instruction (vs 2 segments/instr in the previous float4 layout).
// 20 independent idx->gather chains give ample MLP; indices are
// wave-uniform loads (broadcast). One dwordx2 store per lane at the end.
// Grid: 8192 rows -> 2048 blocks x 256 threads (4 waves/block),
// 8 blocks/CU -> 32 waves/CU.
__global__ __launch_bounds__(256) void emb_pool_kernel(
    const int* __restrict__ indices,   // [F, B, L] int32
    const float* __restrict__ table0,  // [V, D]
    const float* __restrict__ table1,  // [V, D]
    float* __restrict__ out)           // [B, F*D]
{
    const int row  = blockIdx.x * 4 + (threadIdx.x >> 6);  // (f,b) pair id
    const int lane = threadIdx.x & 63;                     // float2 slot

    const int f = row >> 12;          // row / 4096
    const int b = row & (BATCH - 1);  // row % 4096

    const float* __restrict__ tab = (f == 0) ? table0 : table1;
    const int* __restrict__ idxp = indices + (size_t)row * BAG;

    float2 acc = make_float2(0.f, 0.f);
    #pragma unroll
    for (int l = 0; l < BAG; ++l) {
        const int idx = idxp[l];   // wave-uniform -> broadcast load
        const float2 v =
            reinterpret_cast<const float2*>(tab + (size_t)idx * DIM)[lane];
        acc.x += v.x; acc.y += v.y;
    }

    reinterpret_cast<float2*>(
        out + (size_t)b * (NFEAT * DIM) + f * DIM)[lane] = acc;
}

extern "C" void kernel_launch(void* const* d_in, const int* in_sizes, int n_in,
                              void* d_out, int out_size, void* d_ws, size_t ws_size,
                              hipStream_t stream) {
    const int*   indices = (const int*)d_in[0];
    const float* table0  = (const float*)d_in[1];
    const float* table1  = (const float*)d_in[2];
    float*       out     = (float*)d_out;

    const int rows   = NFEAT * BATCH;  // 8192 waves
    const int blocks = rows / 4;       // 2048 blocks of 256 threads (4 waves)
    emb_pool_kernel<<<blocks, 256, 0, stream>>>(indices, table0, table1, out);
}